// Round 1
// baseline (1052.574 us; speedup 1.0000x reference)
//
#include <hip/hip_runtime.h>
#include <hip/hip_bf16.h>

typedef __attribute__((ext_vector_type(8))) __bf16 bf16x8;
typedef __attribute__((ext_vector_type(4))) float f32x4;

// ---------------------------------------------------------------------------
// async global->LDS, 16B per lane. LDS dest is wave-uniform base + lane*16.
// ---------------------------------------------------------------------------
__device__ __forceinline__ void gload_lds16(const void* g, void* lds) {
    __builtin_amdgcn_global_load_lds(
        (const __attribute__((address_space(1))) void*)g,
        (__attribute__((address_space(3))) void*)lds,
        16, 0, 0);
}

// ---------------------------------------------------------------------------
// Block-wise (64) symmetric int5 MSE quant-dequant, f32 math matching the
// reference; writes dequantized weights as bf16.
// One thread per 64-element block; data held in registers.
// ---------------------------------------------------------------------------
__global__ __launch_bounds__(256) void quant_bf16_kernel(
    const float* __restrict__ w, __hip_bfloat16* __restrict__ wq, int nblk)
{
#pragma clang fp contract(off)
    int b = blockIdx.x * 256 + threadIdx.x;
    if (b >= nblk) return;
    const float4* src = (const float4*)(w + (size_t)b * 64);
    float v[64];
#pragma unroll
    for (int i = 0; i < 16; ++i) {
        float4 t = src[i];
        v[i * 4 + 0] = t.x; v[i * 4 + 1] = t.y;
        v[i * 4 + 2] = t.z; v[i * 4 + 3] = t.w;
    }
    float amax = 0.0f;
#pragma unroll
    for (int i = 0; i < 64; ++i) amax = fmaxf(amax, fabsf(v[i]));
    float base = fmaxf(amax, 1e-8f) / 15.0f;

    float best_err = __builtin_inff();
    float best_scale = base;
    for (int k = 0; k < 16; ++k) {
        // np.linspace(0.4, 1.0, 16): y = k*step + 0.4 in f64, y[15]=1.0, cast f32
        double sd = (k == 15) ? 1.0 : ((double)k * (0.6 / 15.0) + 0.4);
        float scale = base * (float)sd;
        float err = 0.0f;
#pragma unroll
        for (int i = 0; i < 64; ++i) {
            float q = rintf(v[i] / scale);          // round-half-even like jnp.round
            q = fminf(fmaxf(q, -15.0f), 15.0f);
            float deq = q * scale;
            float d = deq - v[i];
            err = err + d * d;                      // no FMA contraction
        }
        if (err < best_err) { best_err = err; best_scale = scale; }
    }

    __hip_bfloat16* dst = wq + (size_t)b * 64;
#pragma unroll
    for (int i = 0; i < 64; ++i) {
        float q = rintf(v[i] / best_scale);
        q = fminf(fmaxf(q, -15.0f), 15.0f);
        dst[i] = __float2bfloat16(q * best_scale);
    }
}

// ---------------------------------------------------------------------------
// f32 -> bf16 conversion, 8 elems/thread, 16B stores.
// ---------------------------------------------------------------------------
__global__ __launch_bounds__(256) void f32_to_bf16_kernel(
    const float* __restrict__ in, __hip_bfloat16* __restrict__ out, int n8)
{
    int i = blockIdx.x * 256 + threadIdx.x;
    if (i >= n8) return;
    const float4* p = (const float4*)(in + (size_t)i * 8);
    float4 a = p[0], b = p[1];
    alignas(16) __hip_bfloat16 r[8];
    r[0] = __float2bfloat16(a.x); r[1] = __float2bfloat16(a.y);
    r[2] = __float2bfloat16(a.z); r[3] = __float2bfloat16(a.w);
    r[4] = __float2bfloat16(b.x); r[5] = __float2bfloat16(b.y);
    r[6] = __float2bfloat16(b.z); r[7] = __float2bfloat16(b.w);
    *(uint4*)(out + (size_t)i * 8) = *(const uint4*)r;
}

// ---------------------------------------------------------------------------
// bf16 "bt" GEMM: C[m][n] = sum_k A[m][k] * B[n][k]
// 128x128 tile, BK=32, 256 threads (4 waves, 2x2), 4x4 16x16x32 MFMA frags
// per wave, global_load_lds width=16 staging (m97 structure).
// EPI=0: C = bf16( relu(acc)^2 ),  EPI=1: C = f32 acc
// ---------------------------------------------------------------------------
template <int EPI>
__global__ __launch_bounds__(256) void gemm_bt_kernel(
    const __hip_bfloat16* __restrict__ A,   // M x K row-major
    const __hip_bfloat16* __restrict__ B,   // N x K row-major
    void* __restrict__ Cout,                // M x N
    int M, int N, int K)
{
    __shared__ alignas(16) __hip_bfloat16 As[128 * 32];
    __shared__ alignas(16) __hip_bfloat16 Bs[128 * 32];

    const int t    = threadIdx.x;
    const int lane = t & 63;
    const int w    = t >> 6;
    const int wr   = w >> 1;      // 0..1
    const int wc   = w & 1;       // 0..1
    const int lo   = lane & 15;
    const int hi   = lane >> 4;

    const int nN = N >> 7;
    const int bm = blockIdx.x / nN;
    const int bn = blockIdx.x % nN;
    const size_t rowBase = (size_t)bm << 7;
    const size_t colBase = (size_t)bn << 7;

    // staging: idx q*256+t covers row idx>>2, col8 (idx&3)*8 of the 128x32 tile
    const __hip_bfloat16* Ag0 = A + (rowBase + (size_t)(t >> 2)) * K + (t & 3) * 8;
    const __hip_bfloat16* Bg0 = B + (colBase + (size_t)(t >> 2)) * K + (t & 3) * 8;
    const __hip_bfloat16* Ag1 = Ag0 + (size_t)64 * K;
    const __hip_bfloat16* Bg1 = Bg0 + (size_t)64 * K;

    // wave-uniform LDS staging bases (linear layout matches lane order)
    __hip_bfloat16* AsW  = As + (size_t)w * 64 * 8;
    __hip_bfloat16* BsW  = Bs + (size_t)w * 64 * 8;
    __hip_bfloat16* AsW2 = AsW + 256 * 8;
    __hip_bfloat16* BsW2 = BsW + 256 * 8;

    f32x4 acc[4][4] = {};

    for (int k0 = 0; k0 < K; k0 += 32) {
        gload_lds16(Ag0 + k0, AsW);
        gload_lds16(Ag1 + k0, AsW2);
        gload_lds16(Bg0 + k0, BsW);
        gload_lds16(Bg1 + k0, BsW2);
        __syncthreads();   // drains vmcnt before barrier (compiler-inserted)

        bf16x8 a[4], b[4];
#pragma unroll
        for (int i = 0; i < 4; ++i)
            a[i] = *(const bf16x8*)(As + ((wr * 64 + i * 16 + lo) * 32 + hi * 8));
#pragma unroll
        for (int j = 0; j < 4; ++j)
            b[j] = *(const bf16x8*)(Bs + ((wc * 64 + j * 16 + lo) * 32 + hi * 8));

#pragma unroll
        for (int i = 0; i < 4; ++i)
#pragma unroll
            for (int j = 0; j < 4; ++j)
                acc[i][j] = __builtin_amdgcn_mfma_f32_16x16x32_bf16(
                    a[i], b[j], acc[i][j], 0, 0, 0);

        __syncthreads();
    }

    // epilogue: C/D layout col=lane&15, row=(lane>>4)*4+r  [m89/m91 verified]
    if (EPI == 0) {
        __hip_bfloat16* Cb = (__hip_bfloat16*)Cout;
#pragma unroll
        for (int i = 0; i < 4; ++i)
#pragma unroll
            for (int j = 0; j < 4; ++j)
#pragma unroll
                for (int r = 0; r < 4; ++r) {
                    size_t row = rowBase + wr * 64 + i * 16 + hi * 4 + r;
                    size_t col = colBase + wc * 64 + j * 16 + lo;
                    float v0 = fmaxf(acc[i][j][r], 0.0f);
                    Cb[row * N + col] = __float2bfloat16(v0 * v0);
                }
    } else {
        float* Cf = (float*)Cout;
#pragma unroll
        for (int i = 0; i < 4; ++i)
#pragma unroll
            for (int j = 0; j < 4; ++j)
#pragma unroll
                for (int r = 0; r < 4; ++r) {
                    size_t row = rowBase + wr * 64 + i * 16 + hi * 4 + r;
                    size_t col = colBase + wc * 64 + j * 16 + lo;
                    Cf[row * N + col] = acc[i][j][r];
                }
    }
}

// ---------------------------------------------------------------------------
extern "C" void kernel_launch(void* const* d_in, const int* in_sizes, int n_in,
                              void* d_out, int out_size, void* d_ws, size_t ws_size,
                              hipStream_t stream) {
    const float* x      = (const float*)d_in[0];  // (4,2048,2048) -> 8192 x 2048
    const float* w_fc   = (const float*)d_in[1];  // 8192 x 2048
    const float* w_proj = (const float*)d_in[2];  // 2048 x 8192
    float* out = (float*)d_out;                   // 8192 x 2048

    const int DIM = 2048, HID = 8192, M = 8192;

    char* ws = (char*)d_ws;
    __hip_bfloat16* Xb  = (__hip_bfloat16*)ws;                                  // M*DIM
    __hip_bfloat16* Wfc = (__hip_bfloat16*)(ws + (size_t)M * DIM * 2);          // HID*DIM
    __hip_bfloat16* Wpj = (__hip_bfloat16*)(ws + (size_t)(M * DIM + (size_t)HID * DIM) * 2);
    __hip_bfloat16* H2  = (__hip_bfloat16*)(ws + (size_t)(M * DIM + 2 * (size_t)HID * DIM) * 2);

    // 1) quantize-dequantize weights -> bf16
    int nblk_fc = HID * DIM / 64;  // 262144
    quant_bf16_kernel<<<nblk_fc / 256, 256, 0, stream>>>(w_fc, Wfc, nblk_fc);
    int nblk_pj = DIM * HID / 64;  // 262144
    quant_bf16_kernel<<<nblk_pj / 256, 256, 0, stream>>>(w_proj, Wpj, nblk_pj);

    // 2) x -> bf16
    int n8 = M * DIM / 8;  // 2,097,152
    f32_to_bf16_kernel<<<n8 / 256, 256, 0, stream>>>(x, Xb, n8);

    // 3) H2 = bf16( relu(X @ Wfc^T)^2 )   [8192 x 8192]
    gemm_bt_kernel<0><<<(M / 128) * (HID / 128), 256, 0, stream>>>(
        Xb, Wfc, (void*)H2, M, HID, DIM);

    // 4) out = H2 @ Wpj^T   [8192 x 2048] f32
    gemm_bt_kernel<1><<<(M / 128) * (DIM / 128), 256, 0, stream>>>(
        H2, Wpj, (void*)out, M, DIM, HID);
}

// Round 2
// 784.636 us; speedup vs baseline: 1.3415x; 1.3415x over previous
//
#include <hip/hip_runtime.h>
#include <hip/hip_bf16.h>

typedef __attribute__((ext_vector_type(8))) __bf16 bf16x8;
typedef __attribute__((ext_vector_type(4))) float f32x4;

__device__ __forceinline__ void gload_lds16(const void* g, void* lds) {
    __builtin_amdgcn_global_load_lds(
        (const __attribute__((address_space(1))) void*)g,
        (__attribute__((address_space(3))) void*)lds, 16, 0, 0);
}

// ---------------------------------------------------------------------------
// int5 block-64 MSE quant-dequant -> bf16 (reference-matching f32 math)
// ---------------------------------------------------------------------------
__global__ __launch_bounds__(256) void quant_bf16_kernel(
    const float* __restrict__ w, __hip_bfloat16* __restrict__ wq, int nblk)
{
#pragma clang fp contract(off)
    int b = blockIdx.x * 256 + threadIdx.x;
    if (b >= nblk) return;
    const float4* src = (const float4*)(w + (size_t)b * 64);
    float v[64];
#pragma unroll
    for (int i = 0; i < 16; ++i) {
        float4 t = src[i];
        v[i*4+0] = t.x; v[i*4+1] = t.y; v[i*4+2] = t.z; v[i*4+3] = t.w;
    }
    float amax = 0.0f;
#pragma unroll
    for (int i = 0; i < 64; ++i) amax = fmaxf(amax, fabsf(v[i]));
    float base = fmaxf(amax, 1e-8f) / 15.0f;

    float best_err = __builtin_inff();
    float best_scale = base;
    for (int k = 0; k < 16; ++k) {
        double sd = (k == 15) ? 1.0 : ((double)k * (0.6 / 15.0) + 0.4);
        float scale = base * (float)sd;
        float err = 0.0f;
#pragma unroll
        for (int i = 0; i < 64; ++i) {
            float q = rintf(v[i] / scale);
            q = fminf(fmaxf(q, -15.0f), 15.0f);
            float d = q * scale - v[i];
            err = err + d * d;
        }
        if (err < best_err) { best_err = err; best_scale = scale; }
    }
    __hip_bfloat16* dst = wq + (size_t)b * 64;
#pragma unroll
    for (int i = 0; i < 64; ++i) {
        float q = rintf(v[i] / best_scale);
        q = fminf(fmaxf(q, -15.0f), 15.0f);
        dst[i] = __float2bfloat16(q * best_scale);
    }
}

__global__ __launch_bounds__(256) void f32_to_bf16_kernel(
    const float* __restrict__ in, __hip_bfloat16* __restrict__ out, int n8)
{
    int i = blockIdx.x * 256 + threadIdx.x;
    if (i >= n8) return;
    const float4* p = (const float4*)(in + (size_t)i * 8);
    float4 a = p[0], b = p[1];
    alignas(16) __hip_bfloat16 r[8];
    r[0] = __float2bfloat16(a.x); r[1] = __float2bfloat16(a.y);
    r[2] = __float2bfloat16(a.z); r[3] = __float2bfloat16(a.w);
    r[4] = __float2bfloat16(b.x); r[5] = __float2bfloat16(b.y);
    r[6] = __float2bfloat16(b.z); r[7] = __float2bfloat16(b.w);
    *(uint4*)(out + (size_t)i * 8) = *(const uint4*)r;
}

// ---------------------------------------------------------------------------
// 256x256 tile, BK=64, 512 threads (8 waves = 2Mx4N), 4 phases per K-tile.
// LDS: 2 buffers x (A:2 halves + B:2 halves) x 16KB = 128KB dynamic.
// Half-tile layout: 128 rows x 64 cols bf16, row stride 128B, XOR-swizzled:
//   phys = logical ^ ((row&7)<<4)   (involution; 16B chunks permuted)
// Staging: global_load_lds w=16, LINEAR dest, INVERSE-swizzled global src.
// Hazard ledger:
//  - reads of buf[cur] (tile t): data landed -> per-wave vmcnt(0) at end of
//    tile t-1 phase 3 + barrier (prologue covers t=0).
//  - writes to buf[cur^1] (tile t+1, issued during tile t): last reads of
//    that buffer (tile t-1) completed -> per-wave lgkmcnt(0) in each phase of
//    tile t-1 + final barrier, before any tile-t gload issues.
// ---------------------------------------------------------------------------
template <int EPI>  // 0: C=bf16(relu(acc)^2), 1: C=f32 acc
__global__ __launch_bounds__(512, 1) void gemm256_kernel(
    const __hip_bfloat16* __restrict__ A,   // M x K
    const __hip_bfloat16* __restrict__ B,   // N x K
    void* __restrict__ Cout, int M, int N, int K)
{
    extern __shared__ char smem[];

    const int t    = threadIdx.x;
    const int lane = t & 63;
    const int w    = t >> 6;        // 0..7
    const int wr   = w >> 2;        // 0..1  (128-row half)
    const int wc   = w & 3;         // 0..3  (64-col quarter)
    const int lo   = lane & 15;
    const int hi   = lane >> 4;

    // XCD-aware swizzle (grids here are multiples of 8)
    const int cpx = gridDim.x >> 3;
    int bid = blockIdx.x;
    bid = (bid & 7) * cpx + (bid >> 3);
    const int nN = N >> 8;
    const int bm = bid / nN;
    const int bn = bid % nN;
    const int rowBase = bm << 8;
    const int colBase = bn << 8;

    // ---- staging source (inverse-swizzled), per thread, 2 rounds ----
    uint offA[2], offB[2];
#pragma unroll
    for (int r = 0; r < 2; ++r) {
        uint o = (uint)r * 8192u + (uint)t * 16u;      // linear LDS byte off
        uint p = o ^ (((o >> 7) & 7u) << 4);           // logical byte off
        uint srow = p >> 7;
        uint scol = (p & 127u) >> 1;
        offA[r] = (uint)(rowBase + srow) * (uint)K + scol;
        offB[r] = (uint)(colBase + srow) * (uint)K + scol;
    }
    const uint hG = 128u * (uint)K;   // +128 rows in global

    // ---- LDS read addressing (swizzled) ----
    const uint sw   = (uint)(lo & 7) << 4;
    const uint aB   = (uint)wr * 16384u + (uint)lo * 128u;
    const uint bB   = 32768u + (uint)(wc >> 1) * 16384u
                    + ((uint)(wc & 1) * 64u + (uint)lo) * 128u;
    const uint cb0  = ((uint)hi * 16u) ^ sw;
    const uint cb1  = (64u + (uint)hi * 16u) ^ sw;

    f32x4 acc[8][4] = {};
    bf16x8 bfrag[4][2];

    // ---- prologue: stage tile 0 into buf0, all 4 halves ----
    {
        char* d = smem + (uint)w * 1024u;
#pragma unroll
        for (int r = 0; r < 2; ++r) {
            char* dr = d + r * 8192;
            gload_lds16(A + offA[r],      dr + 0);
            gload_lds16(A + offA[r] + hG, dr + 16384);
            gload_lds16(B + offB[r],      dr + 32768);
            gload_lds16(B + offB[r] + hG, dr + 49152);
        }
    }
    asm volatile("s_waitcnt vmcnt(0)" ::: "memory");
    __builtin_amdgcn_s_barrier();

    const int NT = K >> 6;
    uint k0 = 64;                       // next tile's k (elements)
    for (int tile = 0; tile < NT; ++tile) {
        const uint bufOff = (uint)(tile & 1) * 65536u;
        char* nb = smem + (uint)((tile + 1) & 1) * 65536u;
        const bool pf = (tile + 1 < NT);
#pragma unroll
        for (int ph = 0; ph < 4; ++ph) {
            bf16x8 afrag[2][2];
#pragma unroll
            for (int di = 0; di < 2; ++di) {
                const uint ab = bufOff + aB + (uint)(2*ph + di) * 2048u;
                afrag[di][0] = *(const bf16x8*)(smem + ab + cb0);
                afrag[di][1] = *(const bf16x8*)(smem + ab + cb1);
            }
            if (ph == 0) {
#pragma unroll
                for (int j = 0; j < 4; ++j) {
                    const uint bb = bufOff + bB + (uint)j * 2048u;
                    bfrag[j][0] = *(const bf16x8*)(smem + bb + cb0);
                    bfrag[j][1] = *(const bf16x8*)(smem + bb + cb1);
                }
            }
            if (pf) {   // stage half 'ph' of tile+1 into other buffer
                const __hip_bfloat16* sb = (ph < 2) ? A : B;
                const uint o0 = (ph < 2) ? offA[0] : offB[0];
                const uint o1 = (ph < 2) ? offA[1] : offB[1];
                const uint ha = (ph & 1) ? hG : 0u;
                char* dh = nb + ph * 16384 + (uint)w * 1024u;
                gload_lds16(sb + (size_t)(o0 + ha + k0), dh);
                gload_lds16(sb + (size_t)(o1 + ha + k0), dh + 8192);
            }
            __builtin_amdgcn_s_barrier();
            asm volatile("s_waitcnt lgkmcnt(0)" ::: "memory");
            __builtin_amdgcn_s_setprio(1);
#pragma unroll
            for (int di = 0; di < 2; ++di)
#pragma unroll
                for (int j = 0; j < 4; ++j) {
                    acc[2*ph+di][j] = __builtin_amdgcn_mfma_f32_16x16x32_bf16(
                        afrag[di][0], bfrag[j][0], acc[2*ph+di][j], 0, 0, 0);
                    acc[2*ph+di][j] = __builtin_amdgcn_mfma_f32_16x16x32_bf16(
                        afrag[di][1], bfrag[j][1], acc[2*ph+di][j], 0, 0, 0);
                }
            __builtin_amdgcn_s_setprio(0);
            if (ph == 3) asm volatile("s_waitcnt vmcnt(0)" ::: "memory");
            __builtin_amdgcn_s_barrier();
        }
        k0 += 64;
    }

    // ---- epilogue: C/D layout col=lane&15, row=(lane>>4)*4+r ----
    if (EPI == 0) {
        __hip_bfloat16* Cb = (__hip_bfloat16*)Cout;
#pragma unroll
        for (int i = 0; i < 8; ++i)
#pragma unroll
            for (int j = 0; j < 4; ++j)
#pragma unroll
                for (int r = 0; r < 4; ++r) {
                    size_t row = rowBase + wr*128 + i*16 + hi*4 + r;
                    size_t col = colBase + wc*64 + j*16 + lo;
                    float v = fmaxf(acc[i][j][r], 0.0f);
                    Cb[row * N + col] = __float2bfloat16(v * v);
                }
    } else {
        float* Cf = (float*)Cout;
#pragma unroll
        for (int i = 0; i < 8; ++i)
#pragma unroll
            for (int j = 0; j < 4; ++j)
#pragma unroll
                for (int r = 0; r < 4; ++r) {
                    size_t row = rowBase + wr*128 + i*16 + hi*4 + r;
                    size_t col = colBase + wc*64 + j*16 + lo;
                    Cf[row * N + col] = acc[i][j][r];
                }
    }
}

// ---------------------------------------------------------------------------
extern "C" void kernel_launch(void* const* d_in, const int* in_sizes, int n_in,
                              void* d_out, int out_size, void* d_ws, size_t ws_size,
                              hipStream_t stream) {
    const float* x      = (const float*)d_in[0];  // 8192 x 2048
    const float* w_fc   = (const float*)d_in[1];  // 8192 x 2048
    const float* w_proj = (const float*)d_in[2];  // 2048 x 8192
    float* out = (float*)d_out;                   // 8192 x 2048

    const int DIM = 2048, HID = 8192, M = 8192;

    char* ws = (char*)d_ws;
    __hip_bfloat16* Xb  = (__hip_bfloat16*)ws;                                  // M*DIM
    __hip_bfloat16* Wfc = (__hip_bfloat16*)(ws + (size_t)M * DIM * 2);
    __hip_bfloat16* Wpj = (__hip_bfloat16*)(ws + (size_t)(M * DIM + (size_t)HID * DIM) * 2);
    __hip_bfloat16* H2  = (__hip_bfloat16*)(ws + (size_t)(M * DIM + 2 * (size_t)HID * DIM) * 2);

    // allow 128KB dynamic LDS (host-side, capture-safe; ignore result)
    (void)hipFuncSetAttribute((const void*)gemm256_kernel<0>,
                              hipFuncAttributeMaxDynamicSharedMemorySize, 131072);
    (void)hipFuncSetAttribute((const void*)gemm256_kernel<1>,
                              hipFuncAttributeMaxDynamicSharedMemorySize, 131072);

    int nblk = HID * DIM / 64;
    quant_bf16_kernel<<<nblk / 256, 256, 0, stream>>>(w_fc, Wfc, nblk);
    quant_bf16_kernel<<<nblk / 256, 256, 0, stream>>>(w_proj, Wpj, nblk);

    int n8 = M * DIM / 8;
    f32_to_bf16_kernel<<<n8 / 256, 256, 0, stream>>>(x, Xb, n8);

    // H2 = bf16( relu(X @ Wfc^T)^2 )  [8192 x 8192]
    gemm256_kernel<0><<<(M/256)*(HID/256), 512, 131072, stream>>>(
        Xb, Wfc, (void*)H2, M, HID, DIM);

    // out = H2 @ Wpj^T  [8192 x 2048] f32
    gemm256_kernel<1><<<(M/256)*(DIM/256), 512, 131072, stream>>>(
        H2, Wpj, (void*)out, M, DIM, HID);
}

// Round 3
// 632.647 us; speedup vs baseline: 1.6638x; 1.2402x over previous
//
#include <hip/hip_runtime.h>
#include <hip/hip_bf16.h>

typedef __attribute__((ext_vector_type(8))) __bf16 bf16x8;
typedef __attribute__((ext_vector_type(4))) float f32x4;

__device__ __forceinline__ void gload_lds16(const void* g, void* lds) {
    __builtin_amdgcn_global_load_lds(
        (const __attribute__((address_space(1))) void*)g,
        (__attribute__((address_space(3))) void*)lds, 16, 0, 0);
}

// ---------------------------------------------------------------------------
// int5 block-64 MSE quant-dequant -> bf16.
// Per-scale reciprocal (16 IEEE divides/thread) replaces 1088 per-element
// divides; q = rintf(v*rs) can differ from rintf(v/scale) only at half-way
// ulp cases -> deq delta O(scale)=4e-3 << 0.21 threshold.
// ---------------------------------------------------------------------------
__global__ __launch_bounds__(256) void quant_bf16_kernel(
    const float* __restrict__ w, __hip_bfloat16* __restrict__ wq, int nblk)
{
#pragma clang fp contract(off)
    int b = blockIdx.x * 256 + threadIdx.x;
    if (b >= nblk) return;
    const float4* src = (const float4*)(w + (size_t)b * 64);
    float v[64];
#pragma unroll
    for (int i = 0; i < 16; ++i) {
        float4 t = src[i];
        v[i*4+0] = t.x; v[i*4+1] = t.y; v[i*4+2] = t.z; v[i*4+3] = t.w;
    }
    float amax = 0.0f;
#pragma unroll
    for (int i = 0; i < 64; ++i) amax = fmaxf(amax, fabsf(v[i]));
    float base = fmaxf(amax, 1e-8f) / 15.0f;

    float best_err = __builtin_inff();
    float best_scale = base, best_rs = 0.0f;
    for (int k = 0; k < 16; ++k) {
        // np.linspace(0.4,1.0,16): y[k]=k*(0.6/15)+0.4 in f64, y[15]=1.0 exact
        double sd = (k == 15) ? 1.0 : ((double)k * (0.6 / 15.0) + 0.4);
        float scale = base * (float)sd;
        float rs = 1.0f / scale;
        float err = 0.0f;
#pragma unroll
        for (int i = 0; i < 64; ++i) {
            float q = rintf(v[i] * rs);
            q = fminf(fmaxf(q, -15.0f), 15.0f);
            float d = q * scale - v[i];
            err = err + d * d;
        }
        if (err < best_err) { best_err = err; best_scale = scale; best_rs = rs; }
    }
    __hip_bfloat16* dst = wq + (size_t)b * 64;
#pragma unroll
    for (int i = 0; i < 64; ++i) {
        float q = rintf(v[i] * best_rs);
        q = fminf(fmaxf(q, -15.0f), 15.0f);
        dst[i] = __float2bfloat16(q * best_scale);
    }
}

__global__ __launch_bounds__(256) void f32_to_bf16_kernel(
    const float* __restrict__ in, __hip_bfloat16* __restrict__ out, int n8)
{
    int i = blockIdx.x * 256 + threadIdx.x;
    if (i >= n8) return;
    const float4* p = (const float4*)(in + (size_t)i * 8);
    float4 a = p[0], b = p[1];
    alignas(16) __hip_bfloat16 r[8];
    r[0] = __float2bfloat16(a.x); r[1] = __float2bfloat16(a.y);
    r[2] = __float2bfloat16(a.z); r[3] = __float2bfloat16(a.w);
    r[4] = __float2bfloat16(b.x); r[5] = __float2bfloat16(b.y);
    r[6] = __float2bfloat16(b.z); r[7] = __float2bfloat16(b.w);
    *(uint4*)(out + (size_t)i * 8) = *(const uint4*)r;
}

// ---------------------------------------------------------------------------
// 256x256 tile, BK=64, 512 threads (8 waves = 2Mx4N), 4 phases per K-tile.
// LDS: 2 buffers x 64KB, XOR-swizzled (phys = logical ^ ((row&7)<<4)),
// staged via global_load_lds w=16 with inverse-swizzled global sources.
// Prefetch: ALL 8 loads for tile t+1 issued at phase 0 of tile t; single
// vmcnt(0) at end of phase 3 -> ~3 MFMA phases of latency cover.
// Hazard ledger:
//  - reads of buf[cur] (tile t): loads issued tile t-1 ph0, drained by
//    vmcnt(0) at t-1 ph3 + barrier (prologue covers t=0).
//  - writes to buf[cur^1] at tile t ph0: that buffer's last readers (tile
//    t-1) each did lgkmcnt(0) before t-1's final barrier -> safe.
// ---------------------------------------------------------------------------
template <int EPI>  // 0: C=bf16(relu(acc)^2), 1: C=f32 acc
__global__ __launch_bounds__(512, 1) void gemm256_kernel(
    const __hip_bfloat16* __restrict__ A,   // M x K
    const __hip_bfloat16* __restrict__ B,   // N x K
    void* __restrict__ Cout, int M, int N, int K)
{
    extern __shared__ char smem[];

    const int t    = threadIdx.x;
    const int lane = t & 63;
    const int w    = t >> 6;        // 0..7
    const int wr   = w >> 2;        // 0..1  (128-row half)
    const int wc   = w & 3;         // 0..3  (64-col quarter)
    const int lo   = lane & 15;
    const int hi   = lane >> 4;

    // XCD-aware swizzle (grids here are multiples of 8)
    const int cpx = gridDim.x >> 3;
    int bid = blockIdx.x;
    bid = (bid & 7) * cpx + (bid >> 3);
    const int nN = N >> 8;
    const int bm = bid / nN;
    const int bn = bid % nN;
    const int rowBase = bm << 8;
    const int colBase = bn << 8;

    // ---- staging source (inverse-swizzled), per thread, 2 rounds ----
    uint offA[2], offB[2];
#pragma unroll
    for (int r = 0; r < 2; ++r) {
        uint o = (uint)r * 8192u + (uint)t * 16u;      // linear LDS byte off
        uint p = o ^ (((o >> 7) & 7u) << 4);           // logical byte off
        uint srow = p >> 7;
        uint scol = (p & 127u) >> 1;
        offA[r] = (uint)(rowBase + srow) * (uint)K + scol;
        offB[r] = (uint)(colBase + srow) * (uint)K + scol;
    }
    const uint hG = 128u * (uint)K;   // +128 rows in global

    // ---- LDS read addressing (swizzled) ----
    const uint sw   = (uint)(lo & 7) << 4;
    const uint aB   = (uint)wr * 16384u + (uint)lo * 128u;
    const uint bB   = 32768u + (uint)(wc >> 1) * 16384u
                    + ((uint)(wc & 1) * 64u + (uint)lo) * 128u;
    const uint cb0  = ((uint)hi * 16u) ^ sw;
    const uint cb1  = (64u + (uint)hi * 16u) ^ sw;

    f32x4 acc[8][4] = {};
    bf16x8 bfrag[4][2];

    // ---- prologue: stage tile 0 into buf0, all 4 halves ----
    {
        char* d = smem + (uint)w * 1024u;
#pragma unroll
        for (int r = 0; r < 2; ++r) {
            char* dr = d + r * 8192;
            gload_lds16(A + offA[r],      dr + 0);
            gload_lds16(A + offA[r] + hG, dr + 16384);
            gload_lds16(B + offB[r],      dr + 32768);
            gload_lds16(B + offB[r] + hG, dr + 49152);
        }
    }
    asm volatile("s_waitcnt vmcnt(0)" ::: "memory");
    __builtin_amdgcn_s_barrier();

    const int NT = K >> 6;
    uint k0 = 64;                       // next tile's k (elements)
    for (int tile = 0; tile < NT; ++tile) {
        const uint bufOff = (uint)(tile & 1) * 65536u;
        char* nb = smem + (uint)((tile + 1) & 1) * 65536u;
        const bool pf = (tile + 1 < NT);
#pragma unroll
        for (int ph = 0; ph < 4; ++ph) {
            bf16x8 afrag[2][2];
#pragma unroll
            for (int di = 0; di < 2; ++di) {
                const uint ab = bufOff + aB + (uint)(2*ph + di) * 2048u;
                afrag[di][0] = *(const bf16x8*)(smem + ab + cb0);
                afrag[di][1] = *(const bf16x8*)(smem + ab + cb1);
            }
            if (ph == 0) {
#pragma unroll
                for (int j = 0; j < 4; ++j) {
                    const uint bb = bufOff + bB + (uint)j * 2048u;
                    bfrag[j][0] = *(const bf16x8*)(smem + bb + cb0);
                    bfrag[j][1] = *(const bf16x8*)(smem + bb + cb1);
                }
                if (pf) {   // stage ALL of tile+1 into other buffer now
                    char* d = nb + (uint)w * 1024u;
                    gload_lds16(A + (size_t)(offA[0] + k0),      d + 0);
                    gload_lds16(A + (size_t)(offA[1] + k0),      d + 8192);
                    gload_lds16(A + (size_t)(offA[0] + hG + k0), d + 16384);
                    gload_lds16(A + (size_t)(offA[1] + hG + k0), d + 16384 + 8192);
                    gload_lds16(B + (size_t)(offB[0] + k0),      d + 32768);
                    gload_lds16(B + (size_t)(offB[1] + k0),      d + 32768 + 8192);
                    gload_lds16(B + (size_t)(offB[0] + hG + k0), d + 49152);
                    gload_lds16(B + (size_t)(offB[1] + hG + k0), d + 49152 + 8192);
                }
            }
            __builtin_amdgcn_s_barrier();
            asm volatile("s_waitcnt lgkmcnt(0)" ::: "memory");
            __builtin_amdgcn_s_setprio(1);
#pragma unroll
            for (int di = 0; di < 2; ++di)
#pragma unroll
                for (int j = 0; j < 4; ++j) {
                    acc[2*ph+di][j] = __builtin_amdgcn_mfma_f32_16x16x32_bf16(
                        afrag[di][0], bfrag[j][0], acc[2*ph+di][j], 0, 0, 0);
                    acc[2*ph+di][j] = __builtin_amdgcn_mfma_f32_16x16x32_bf16(
                        afrag[di][1], bfrag[j][1], acc[2*ph+di][j], 0, 0, 0);
                }
            __builtin_amdgcn_s_setprio(0);
            if (ph == 3) asm volatile("s_waitcnt vmcnt(0)" ::: "memory");
            __builtin_amdgcn_s_barrier();
        }
        k0 += 64;
    }

    // ---- epilogue: C/D layout col=lane&15, row=(lane>>4)*4+r ----
    if (EPI == 0) {
        __hip_bfloat16* Cb = (__hip_bfloat16*)Cout;
#pragma unroll
        for (int i = 0; i < 8; ++i)
#pragma unroll
            for (int j = 0; j < 4; ++j)
#pragma unroll
                for (int r = 0; r < 4; ++r) {
                    size_t row = rowBase + wr*128 + i*16 + hi*4 + r;
                    size_t col = colBase + wc*64 + j*16 + lo;
                    float v = fmaxf(acc[i][j][r], 0.0f);
                    Cb[row * N + col] = __float2bfloat16(v * v);
                }
    } else {
        float* Cf = (float*)Cout;
#pragma unroll
        for (int i = 0; i < 8; ++i)
#pragma unroll
            for (int j = 0; j < 4; ++j)
#pragma unroll
                for (int r = 0; r < 4; ++r) {
                    size_t row = rowBase + wr*128 + i*16 + hi*4 + r;
                    size_t col = colBase + wc*64 + j*16 + lo;
                    Cf[row * N + col] = acc[i][j][r];
                }
    }
}

// ---------------------------------------------------------------------------
extern "C" void kernel_launch(void* const* d_in, const int* in_sizes, int n_in,
                              void* d_out, int out_size, void* d_ws, size_t ws_size,
                              hipStream_t stream) {
    const float* x      = (const float*)d_in[0];  // 8192 x 2048
    const float* w_fc   = (const float*)d_in[1];  // 8192 x 2048
    const float* w_proj = (const float*)d_in[2];  // 2048 x 8192
    float* out = (float*)d_out;                   // 8192 x 2048

    const int DIM = 2048, HID = 8192, M = 8192;

    char* ws = (char*)d_ws;
    __hip_bfloat16* Xb  = (__hip_bfloat16*)ws;                                  // M*DIM
    __hip_bfloat16* Wfc = (__hip_bfloat16*)(ws + (size_t)M * DIM * 2);
    __hip_bfloat16* Wpj = (__hip_bfloat16*)(ws + (size_t)(M * DIM + (size_t)HID * DIM) * 2);
    __hip_bfloat16* H2  = (__hip_bfloat16*)(ws + (size_t)(M * DIM + 2 * (size_t)HID * DIM) * 2);

    (void)hipFuncSetAttribute((const void*)gemm256_kernel<0>,
                              hipFuncAttributeMaxDynamicSharedMemorySize, 131072);
    (void)hipFuncSetAttribute((const void*)gemm256_kernel<1>,
                              hipFuncAttributeMaxDynamicSharedMemorySize, 131072);

    int nblk = HID * DIM / 64;
    quant_bf16_kernel<<<nblk / 256, 256, 0, stream>>>(w_fc, Wfc, nblk);
    quant_bf16_kernel<<<nblk / 256, 256, 0, stream>>>(w_proj, Wpj, nblk);

    int n8 = M * DIM / 8;
    f32_to_bf16_kernel<<<n8 / 256, 256, 0, stream>>>(x, Xb, n8);

    // H2 = bf16( relu(X @ Wfc^T)^2 )  [8192 x 8192]
    gemm256_kernel<0><<<(M/256)*(HID/256), 512, 131072, stream>>>(
        Xb, Wfc, (void*)H2, M, HID, DIM);

    // out = H2 @ Wpj^T  [8192 x 2048] f32
    gemm256_kernel<1><<<(M/256)*(DIM/256), 512, 131072, stream>>>(
        H2, Wpj, (void*)out, M, DIM, HID);
}

// Round 4
// 611.269 us; speedup vs baseline: 1.7220x; 1.0350x over previous
//
#include <hip/hip_runtime.h>
#include <hip/hip_bf16.h>

typedef __attribute__((ext_vector_type(8))) __bf16 bf16x8;
typedef __attribute__((ext_vector_type(4))) float f32x4;

__device__ __forceinline__ void gload_lds16(const void* g, void* lds) {
    __builtin_amdgcn_global_load_lds(
        (const __attribute__((address_space(1))) void*)g,
        (__attribute__((address_space(3))) void*)lds, 16, 0, 0);
}

// ---------------------------------------------------------------------------
// int5 block-64 MSE quant-dequant -> bf16 (per-scale reciprocal)
// ---------------------------------------------------------------------------
__global__ __launch_bounds__(256) void quant_bf16_kernel(
    const float* __restrict__ w, __hip_bfloat16* __restrict__ wq, int nblk)
{
#pragma clang fp contract(off)
    int b = blockIdx.x * 256 + threadIdx.x;
    if (b >= nblk) return;
    const float4* src = (const float4*)(w + (size_t)b * 64);
    float v[64];
#pragma unroll
    for (int i = 0; i < 16; ++i) {
        float4 t = src[i];
        v[i*4+0] = t.x; v[i*4+1] = t.y; v[i*4+2] = t.z; v[i*4+3] = t.w;
    }
    float amax = 0.0f;
#pragma unroll
    for (int i = 0; i < 64; ++i) amax = fmaxf(amax, fabsf(v[i]));
    float base = fmaxf(amax, 1e-8f) / 15.0f;

    float best_err = __builtin_inff();
    float best_scale = base, best_rs = 0.0f;
    for (int k = 0; k < 16; ++k) {
        double sd = (k == 15) ? 1.0 : ((double)k * (0.6 / 15.0) + 0.4);
        float scale = base * (float)sd;
        float rs = 1.0f / scale;
        float err = 0.0f;
#pragma unroll
        for (int i = 0; i < 64; ++i) {
            float q = rintf(v[i] * rs);
            q = fminf(fmaxf(q, -15.0f), 15.0f);
            float d = q * scale - v[i];
            err = err + d * d;
        }
        if (err < best_err) { best_err = err; best_scale = scale; best_rs = rs; }
    }
    __hip_bfloat16* dst = wq + (size_t)b * 64;
#pragma unroll
    for (int i = 0; i < 64; ++i) {
        float q = rintf(v[i] * best_rs);
        q = fminf(fmaxf(q, -15.0f), 15.0f);
        dst[i] = __float2bfloat16(q * best_scale);
    }
}

__global__ __launch_bounds__(256) void f32_to_bf16_kernel(
    const float* __restrict__ in, __hip_bfloat16* __restrict__ out, int n8)
{
    int i = blockIdx.x * 256 + threadIdx.x;
    if (i >= n8) return;
    const float4* p = (const float4*)(in + (size_t)i * 8);
    float4 a = p[0], b = p[1];
    alignas(16) __hip_bfloat16 r[8];
    r[0] = __float2bfloat16(a.x); r[1] = __float2bfloat16(a.y);
    r[2] = __float2bfloat16(a.z); r[3] = __float2bfloat16(a.w);
    r[4] = __float2bfloat16(b.x); r[5] = __float2bfloat16(b.y);
    r[6] = __float2bfloat16(b.z); r[7] = __float2bfloat16(b.w);
    *(uint4*)(out + (size_t)i * 8) = *(const uint4*)r;
}

// ---------------------------------------------------------------------------
// 256x256 tile, BK=64, 512 threads (8 waves = 2Mx4N). 8-phase schedule over
// K-tile PAIRS: even tiles in buf0 (smem+0), odd in buf1 (smem+64K).
// Phase (h=ph>>2 selects buffer, q=ph&3 selects C-quadrant = M-frags 2q,2q+1):
//   {ds-read A-subtile (+B if q==0); issue 1 half-tile prefetch (2 gloads);
//    barrier; lgkmcnt(0); setprio1; 16 MFMA; setprio0; [vmcnt]; barrier}
// Prefetch slots (WAR-safe: dest region's readers finished >=1 barrier ago):
//   ph0: t(2P+1).A0->buf1  ph1: t(2P+1).A1->buf1   [buf1.A free since prev ph7]
//   ph2: t(2P+2).B0->buf0  ph3: t(2P+2).B1->buf0   [buf0.B read only at ph0]
//   ph4: t(2P+2).A0->buf0  ph5: t(2P+2).A1->buf0   [buf0.A done after ph3]
//   ph6: t(2P+3).B0->buf1  ph7: t(2P+3).B1->buf1   [buf1.B read only at ph4]
// Counted vmcnt (T4): at ph3-end vmcnt(4) -> leaves t(2P+2).B in flight,
// guarantees t(2P+1) fully landed before ph4 reads buf1. At ph7-end vmcnt(4)
// -> leaves t(2P+3).B, guarantees t(2P+2) landed before next ph0 reads buf0.
// Tail (pf=false): ph0/1 still stage t(2P+1).A; ph3-end uses vmcnt(0).
// LDS swizzle: phys = logical ^ ((row&7)<<4), inverse-swizzled global srcs.
// ---------------------------------------------------------------------------
template <int EPI>  // 0: C=bf16(relu(acc)^2), 1: C=f32 acc
__global__ __launch_bounds__(512, 1) void gemm256_kernel(
    const __hip_bfloat16* __restrict__ A,   // M x K
    const __hip_bfloat16* __restrict__ B,   // N x K
    void* __restrict__ Cout, int M, int N, int K)
{
    extern __shared__ char smem[];

    const int t    = threadIdx.x;
    const int lane = t & 63;
    const int w    = t >> 6;        // 0..7
    const int wr   = w >> 2;        // 0..1  (128-row half)
    const int wc   = w & 3;         // 0..3  (64-col quarter)
    const int lo   = lane & 15;
    const int hi   = lane >> 4;
    const uint wOff = (uint)w * 1024u;

    // XCD-aware swizzle (grids are multiples of 8)
    const int cpx = gridDim.x >> 3;
    int bid = blockIdx.x;
    bid = (bid & 7) * cpx + (bid >> 3);
    const int nN = N >> 8;
    const int bm = bid / nN;
    const int bn = bid % nN;
    const int rowBase = bm << 8;
    const int colBase = bn << 8;

    // staging sources (inverse-swizzled), 2 rounds of 512x16B per half-tile
    uint offA0, offA1, offB0, offB1;
    {
        uint o0 = (uint)t * 16u;
        uint o1 = 8192u + (uint)t * 16u;
        uint p0 = o0 ^ (((o0 >> 7) & 7u) << 4);
        uint p1 = o1 ^ (((o1 >> 7) & 7u) << 4);
        uint r0 = p0 >> 7, c0 = (p0 & 127u) >> 1;
        uint r1 = p1 >> 7, c1 = (p1 & 127u) >> 1;
        offA0 = (uint)(rowBase + r0) * (uint)K + c0;
        offA1 = (uint)(rowBase + r1) * (uint)K + c1;
        offB0 = (uint)(colBase + r0) * (uint)K + c0;
        offB1 = (uint)(colBase + r1) * (uint)K + c1;
    }
    const uint hG = 128u * (uint)K;   // +128 rows in global

    // LDS read addressing (swizzled)
    const uint sw  = (uint)(lo & 7) << 4;
    const uint aB  = (uint)wr * 16384u + (uint)lo * 128u;
    const uint bB  = 32768u + (uint)(wc >> 1) * 16384u
                   + ((uint)(wc & 1) * 64u + (uint)lo) * 128u;
    const uint cb0 = ((uint)hi * 16u) ^ sw;
    const uint cb1 = (64u + (uint)hi * 16u) ^ sw;

    f32x4 acc[8][4] = {};
    bf16x8 bfrag[4][2];

    // ---- prologue: tile0 full -> buf0; tile1.B -> buf1 ----
    gload_lds16(A + (size_t)offA0,        smem + 0     + wOff);
    gload_lds16(A + (size_t)offA1,        smem + 8192  + wOff);
    gload_lds16(A + (size_t)(offA0 + hG), smem + 16384 + wOff);
    gload_lds16(A + (size_t)(offA1 + hG), smem + 24576 + wOff);
    gload_lds16(B + (size_t)offB0,        smem + 32768 + wOff);
    gload_lds16(B + (size_t)offB1,        smem + 40960 + wOff);
    gload_lds16(B + (size_t)(offB0 + hG), smem + 49152 + wOff);
    gload_lds16(B + (size_t)(offB1 + hG), smem + 57344 + wOff);
    gload_lds16(B + (size_t)(offB0 + 64),      smem + 65536 + 32768 + wOff);
    gload_lds16(B + (size_t)(offB1 + 64),      smem + 65536 + 40960 + wOff);
    gload_lds16(B + (size_t)(offB0 + hG + 64), smem + 65536 + 49152 + wOff);
    gload_lds16(B + (size_t)(offB1 + hG + 64), smem + 65536 + 57344 + wOff);
    asm volatile("s_waitcnt vmcnt(4)" ::: "memory");   // tile0 landed
    __builtin_amdgcn_s_barrier();

    const int NI = K >> 7;                  // K-tile pairs
    for (int P = 0; P < NI; ++P) {
        const bool pf = (P + 1 < NI);
        const uint kN1 = ((uint)(2 * P + 1)) << 6;   // tile 2P+1 k-offset
        const uint kN2 = kN1 + 64;
        const uint kN3 = kN1 + 128;
#pragma unroll
        for (int ph = 0; ph < 8; ++ph) {
            const int q = ph & 3;
            const uint bufOff = (uint)(ph >> 2) * 65536u;
            bf16x8 afrag[2][2];
#pragma unroll
            for (int di = 0; di < 2; ++di) {
                const uint ab = bufOff + aB + (uint)(2 * q + di) * 2048u;
                afrag[di][0] = *(const bf16x8*)(smem + ab + cb0);
                afrag[di][1] = *(const bf16x8*)(smem + ab + cb1);
            }
            if (q == 0) {
#pragma unroll
                for (int j = 0; j < 4; ++j) {
                    const uint bb = bufOff + bB + (uint)j * 2048u;
                    bfrag[j][0] = *(const bf16x8*)(smem + bb + cb0);
                    bfrag[j][1] = *(const bf16x8*)(smem + bb + cb1);
                }
            }
            // prefetch slot
            if (ph == 0) {
                gload_lds16(A + (size_t)(offA0 + kN1), smem + 65536 + 0    + wOff);
                gload_lds16(A + (size_t)(offA1 + kN1), smem + 65536 + 8192 + wOff);
            } else if (ph == 1) {
                gload_lds16(A + (size_t)(offA0 + hG + kN1), smem + 65536 + 16384 + wOff);
                gload_lds16(A + (size_t)(offA1 + hG + kN1), smem + 65536 + 24576 + wOff);
            } else if (ph == 2) { if (pf) {
                gload_lds16(B + (size_t)(offB0 + kN2), smem + 32768 + wOff);
                gload_lds16(B + (size_t)(offB1 + kN2), smem + 40960 + wOff); }
            } else if (ph == 3) { if (pf) {
                gload_lds16(B + (size_t)(offB0 + hG + kN2), smem + 49152 + wOff);
                gload_lds16(B + (size_t)(offB1 + hG + kN2), smem + 57344 + wOff); }
            } else if (ph == 4) { if (pf) {
                gload_lds16(A + (size_t)(offA0 + kN2), smem + 0    + wOff);
                gload_lds16(A + (size_t)(offA1 + kN2), smem + 8192 + wOff); }
            } else if (ph == 5) { if (pf) {
                gload_lds16(A + (size_t)(offA0 + hG + kN2), smem + 16384 + wOff);
                gload_lds16(A + (size_t)(offA1 + hG + kN2), smem + 24576 + wOff); }
            } else if (ph == 6) { if (pf) {
                gload_lds16(B + (size_t)(offB0 + kN3), smem + 65536 + 32768 + wOff);
                gload_lds16(B + (size_t)(offB1 + kN3), smem + 65536 + 40960 + wOff); }
            } else { if (pf) {
                gload_lds16(B + (size_t)(offB0 + hG + kN3), smem + 65536 + 49152 + wOff);
                gload_lds16(B + (size_t)(offB1 + hG + kN3), smem + 65536 + 57344 + wOff); }
            }

            __builtin_amdgcn_s_barrier();
            asm volatile("s_waitcnt lgkmcnt(0)" ::: "memory");
            __builtin_amdgcn_s_setprio(1);
#pragma unroll
            for (int di = 0; di < 2; ++di)
#pragma unroll
                for (int j = 0; j < 4; ++j) {
                    acc[2*q+di][j] = __builtin_amdgcn_mfma_f32_16x16x32_bf16(
                        afrag[di][0], bfrag[j][0], acc[2*q+di][j], 0, 0, 0);
                    acc[2*q+di][j] = __builtin_amdgcn_mfma_f32_16x16x32_bf16(
                        afrag[di][1], bfrag[j][1], acc[2*q+di][j], 0, 0, 0);
                }
            __builtin_amdgcn_s_setprio(0);
            if (ph == 3) {
                if (pf) asm volatile("s_waitcnt vmcnt(4)" ::: "memory");
                else    asm volatile("s_waitcnt vmcnt(0)" ::: "memory");
            } else if (ph == 7) {
                if (pf) asm volatile("s_waitcnt vmcnt(4)" ::: "memory");
            }
            __builtin_amdgcn_s_barrier();
        }
    }

    // ---- epilogue: C/D layout col=lane&15, row=(lane>>4)*4+r ----
    if (EPI == 0) {
        __hip_bfloat16* Cb = (__hip_bfloat16*)Cout;
#pragma unroll
        for (int i = 0; i < 8; ++i)
#pragma unroll
            for (int j = 0; j < 4; ++j)
#pragma unroll
                for (int r = 0; r < 4; ++r) {
                    size_t row = rowBase + wr*128 + i*16 + hi*4 + r;
                    size_t col = colBase + wc*64 + j*16 + lo;
                    float v = fmaxf(acc[i][j][r], 0.0f);
                    Cb[row * N + col] = __float2bfloat16(v * v);
                }
    } else {
        float* Cf = (float*)Cout;
#pragma unroll
        for (int i = 0; i < 8; ++i)
#pragma unroll
            for (int j = 0; j < 4; ++j)
#pragma unroll
                for (int r = 0; r < 4; ++r) {
                    size_t row = rowBase + wr*128 + i*16 + hi*4 + r;
                    size_t col = colBase + wc*64 + j*16 + lo;
                    Cf[row * N + col] = acc[i][j][r];
                }
    }
}

// ---------------------------------------------------------------------------
extern "C" void kernel_launch(void* const* d_in, const int* in_sizes, int n_in,
                              void* d_out, int out_size, void* d_ws, size_t ws_size,
                              hipStream_t stream) {
    const float* x      = (const float*)d_in[0];  // 8192 x 2048
    const float* w_fc   = (const float*)d_in[1];  // 8192 x 2048
    const float* w_proj = (const float*)d_in[2];  // 2048 x 8192
    float* out = (float*)d_out;                   // 8192 x 2048

    const int DIM = 2048, HID = 8192, M = 8192;

    char* ws = (char*)d_ws;
    __hip_bfloat16* Xb  = (__hip_bfloat16*)ws;
    __hip_bfloat16* Wfc = (__hip_bfloat16*)(ws + (size_t)M * DIM * 2);
    __hip_bfloat16* Wpj = (__hip_bfloat16*)(ws + (size_t)(M * DIM + (size_t)HID * DIM) * 2);
    __hip_bfloat16* H2  = (__hip_bfloat16*)(ws + (size_t)(M * DIM + 2 * (size_t)HID * DIM) * 2);

    (void)hipFuncSetAttribute((const void*)gemm256_kernel<0>,
                              hipFuncAttributeMaxDynamicSharedMemorySize, 131072);
    (void)hipFuncSetAttribute((const void*)gemm256_kernel<1>,
                              hipFuncAttributeMaxDynamicSharedMemorySize, 131072);

    int nblk = HID * DIM / 64;
    quant_bf16_kernel<<<nblk / 256, 256, 0, stream>>>(w_fc, Wfc, nblk);
    quant_bf16_kernel<<<nblk / 256, 256, 0, stream>>>(w_proj, Wpj, nblk);

    int n8 = M * DIM / 8;
    f32_to_bf16_kernel<<<n8 / 256, 256, 0, stream>>>(x, Xb, n8);

    // H2 = bf16( relu(X @ Wfc^T)^2 )  [8192 x 8192]
    gemm256_kernel<0><<<(M/256)*(HID/256), 512, 131072, stream>>>(
        Xb, Wfc, (void*)H2, M, HID, DIM);

    // out = H2 @ Wpj^T  [8192 x 2048] f32
    gemm256_kernel<1><<<(M/256)*(DIM/256), 512, 131072, stream>>>(
        H2, Wpj, (void*)out, M, DIM, HID);
}

// Round 5
// 590.077 us; speedup vs baseline: 1.7838x; 1.0359x over previous
//
#include <hip/hip_runtime.h>
#include <hip/hip_bf16.h>

typedef __attribute__((ext_vector_type(8))) __bf16 bf16x8;
typedef __attribute__((ext_vector_type(4))) float f32x4;

__device__ __forceinline__ void gload_lds16(const void* g, void* lds) {
    __builtin_amdgcn_global_load_lds(
        (const __attribute__((address_space(1))) void*)g,
        (__attribute__((address_space(3))) void*)lds, 16, 0, 0);
}

// ---------------------------------------------------------------------------
// int5 block-64 MSE quant-dequant -> bf16 (per-scale reciprocal)
// ---------------------------------------------------------------------------
__global__ __launch_bounds__(256) void quant_bf16_kernel(
    const float* __restrict__ w, __hip_bfloat16* __restrict__ wq, int nblk)
{
#pragma clang fp contract(off)
    int b = blockIdx.x * 256 + threadIdx.x;
    if (b >= nblk) return;
    const float4* src = (const float4*)(w + (size_t)b * 64);
    float v[64];
#pragma unroll
    for (int i = 0; i < 16; ++i) {
        float4 t = src[i];
        v[i*4+0] = t.x; v[i*4+1] = t.y; v[i*4+2] = t.z; v[i*4+3] = t.w;
    }
    float amax = 0.0f;
#pragma unroll
    for (int i = 0; i < 64; ++i) amax = fmaxf(amax, fabsf(v[i]));
    float base = fmaxf(amax, 1e-8f) / 15.0f;

    float best_err = __builtin_inff();
    float best_scale = base, best_rs = 0.0f;
    for (int k = 0; k < 16; ++k) {
        double sd = (k == 15) ? 1.0 : ((double)k * (0.6 / 15.0) + 0.4);
        float scale = base * (float)sd;
        float rs = 1.0f / scale;
        float err = 0.0f;
#pragma unroll
        for (int i = 0; i < 64; ++i) {
            float q = rintf(v[i] * rs);
            q = fminf(fmaxf(q, -15.0f), 15.0f);
            float d = q * scale - v[i];
            err = err + d * d;
        }
        if (err < best_err) { best_err = err; best_scale = scale; best_rs = rs; }
    }
    __hip_bfloat16* dst = wq + (size_t)b * 64;
#pragma unroll
    for (int i = 0; i < 64; ++i) {
        float q = rintf(v[i] * best_rs);
        q = fminf(fmaxf(q, -15.0f), 15.0f);
        dst[i] = __float2bfloat16(q * best_scale);
    }
}

__global__ __launch_bounds__(256) void f32_to_bf16_kernel(
    const float* __restrict__ in, __hip_bfloat16* __restrict__ out, int n8)
{
    int i = blockIdx.x * 256 + threadIdx.x;
    if (i >= n8) return;
    const float4* p = (const float4*)(in + (size_t)i * 8);
    float4 a = p[0], b = p[1];
    alignas(16) __hip_bfloat16 r[8];
    r[0] = __float2bfloat16(a.x); r[1] = __float2bfloat16(a.y);
    r[2] = __float2bfloat16(a.z); r[3] = __float2bfloat16(a.w);
    r[4] = __float2bfloat16(b.x); r[5] = __float2bfloat16(b.y);
    r[6] = __float2bfloat16(b.z); r[7] = __float2bfloat16(b.w);
    *(uint4*)(out + (size_t)i * 8) = *(const uint4*)r;
}

// ---------------------------------------------------------------------------
// 256x256 tile, BK=64, 8 waves (2Mx4N). 8 windows per K-tile PAIR:
// windows 0-3 compute buf0 (tile 2P), 4-7 buf1 (tile 2P+1); window ph does
// acc rows {2q,2q+1}, q=ph&3. ONE barrier per window. Fragments for window
// ph+1 are ds_read'd inside window ph right after the MFMAs that free them
// (in-place reload of aC0/aC1; bf reloaded at W3/W7) -> LDS drain overlaps
// MFMA. Staging slots (2 gloads each; unchanged from r4):
//   W0/W1: t+1.A -> buf1.A   W2/W3: t+2.B -> buf0.B
//   W4/W5: t+2.A -> buf0.A   W6/W7: t+3.B -> buf1.B
// RAW guard: vmcnt(2) at END of W2 (guarantees t+1.A + t+1.B landed, leaves
// W2's pair) and END of W6 (guarantees t+2.A + t+2.B, leaves W6's pair),
// each followed by the window barrier -> W3/W7 cross-buffer reads safe.
// WAR guard (1 barrier/window suffices): region staged in window p had its
// last ds_reads issued in p-2 and completed before the reader's MFMA in p-1
// (lgkm dataflow), hence before that wave passed barrier(p-1), hence before
// any wave issues stagings in window p.
// Steady-state outstanding gloads/wave: enter iter 4; W0->6 W1->8 W2->10
// vmcnt(2)->2; W3->4 W4->6 W5->8 W6->10 vmcnt(2)->2; W7->4. Tail: vmcnt(0)
// at W2-end, no W6 vmcnt, no W7 reloads.
// ---------------------------------------------------------------------------
#define LDA2(d, base, s) { \
    d[0] = *(const bf16x8*)(smem + (base) + aB + (s)*2048u + cb0); \
    d[1] = *(const bf16x8*)(smem + (base) + aB + (s)*2048u + cb1); }

#define LDB8(base) { \
    bf[0][0] = *(const bf16x8*)(smem + (base) + bB + 0u    + cb0); \
    bf[0][1] = *(const bf16x8*)(smem + (base) + bB + 0u    + cb1); \
    bf[1][0] = *(const bf16x8*)(smem + (base) + bB + 2048u + cb0); \
    bf[1][1] = *(const bf16x8*)(smem + (base) + bB + 2048u + cb1); \
    bf[2][0] = *(const bf16x8*)(smem + (base) + bB + 4096u + cb0); \
    bf[2][1] = *(const bf16x8*)(smem + (base) + bB + 4096u + cb1); \
    bf[3][0] = *(const bf16x8*)(smem + (base) + bB + 6144u + cb0); \
    bf[3][1] = *(const bf16x8*)(smem + (base) + bB + 6144u + cb1); }

#define MF8(q, a2) { \
    acc[q][0] = __builtin_amdgcn_mfma_f32_16x16x32_bf16(a2[0], bf[0][0], acc[q][0],0,0,0); \
    acc[q][0] = __builtin_amdgcn_mfma_f32_16x16x32_bf16(a2[1], bf[0][1], acc[q][0],0,0,0); \
    acc[q][1] = __builtin_amdgcn_mfma_f32_16x16x32_bf16(a2[0], bf[1][0], acc[q][1],0,0,0); \
    acc[q][1] = __builtin_amdgcn_mfma_f32_16x16x32_bf16(a2[1], bf[1][1], acc[q][1],0,0,0); \
    acc[q][2] = __builtin_amdgcn_mfma_f32_16x16x32_bf16(a2[0], bf[2][0], acc[q][2],0,0,0); \
    acc[q][2] = __builtin_amdgcn_mfma_f32_16x16x32_bf16(a2[1], bf[2][1], acc[q][2],0,0,0); \
    acc[q][3] = __builtin_amdgcn_mfma_f32_16x16x32_bf16(a2[0], bf[3][0], acc[q][3],0,0,0); \
    acc[q][3] = __builtin_amdgcn_mfma_f32_16x16x32_bf16(a2[1], bf[3][1], acc[q][3],0,0,0); }

#define STAGE(base, eoff, ldsOff) \
    gload_lds16((base) + (size_t)((eoff) + voff), smem + (ldsOff) + wOff)

#define BARRIER() { __builtin_amdgcn_sched_barrier(0); \
    __builtin_amdgcn_s_barrier(); __builtin_amdgcn_sched_barrier(0); }

template <int EPI>  // 0: C=bf16(relu(acc)^2), 1: C=f32 acc
__global__ __launch_bounds__(512, 1) void gemm256_kernel(
    const __hip_bfloat16* __restrict__ A,   // M x K
    const __hip_bfloat16* __restrict__ B,   // N x K
    void* __restrict__ Cout, int M, int N, int K)
{
    extern __shared__ char smem[];

    const int t    = threadIdx.x;
    const int lane = t & 63;
    const int w    = t >> 6;
    const int wr   = w >> 2;
    const int wc   = w & 3;
    const int lo   = lane & 15;
    const int hi   = lane >> 4;
    const uint wOff = (uint)w * 1024u;

    const int cpx = gridDim.x >> 3;
    int bid = blockIdx.x;
    bid = (bid & 7) * cpx + (bid >> 3);
    const int nN = N >> 8;
    const int bm = bid / nN;
    const int bn = bid % nN;
    const int rowBase = bm << 8;
    const int colBase = bn << 8;

    // uniform bases + single per-thread staging offset (inverse-swizzled)
    const __hip_bfloat16* uA = A + (size_t)rowBase * (size_t)K;
    const __hip_bfloat16* uB = B + (size_t)colBase * (size_t)K;
    uint o0 = (uint)t * 16u;
    uint p0 = o0 ^ (((o0 >> 7) & 7u) << 4);
    const uint voff = (p0 >> 7) * (uint)K + ((p0 & 127u) >> 1);
    const uint K64 = (uint)K * 64u;      // 64 rows stride (elements)

    // LDS read addressing (swizzled)
    const uint sw  = (uint)(lo & 7) << 4;
    const uint aB  = (uint)wr * 16384u + (uint)lo * 128u;
    const uint bB  = 32768u + (uint)(wc >> 1) * 16384u
                   + ((uint)(wc & 1) * 64u + (uint)lo) * 128u;
    const uint cb0 = ((uint)hi * 16u) ^ sw;
    const uint cb1 = (64u + (uint)hi * 16u) ^ sw;

    f32x4 acc[8][4] = {};
    bf16x8 aC0[2], aC1[2], bf[4][2];

    // ---- prologue: tile0 (A+B) -> buf0, tile1.B -> buf1.B ----
    STAGE(uA, 0u,        0u);       STAGE(uA, K64,        8192u);
    STAGE(uA, 2u*K64,    16384u);   STAGE(uA, 3u*K64,     24576u);
    STAGE(uB, 0u,        32768u);   STAGE(uB, K64,        40960u);
    STAGE(uB, 2u*K64,    49152u);   STAGE(uB, 3u*K64,     57344u);
    STAGE(uB, 64u,           98304u);  STAGE(uB, K64 + 64u,     106496u);
    STAGE(uB, 2u*K64 + 64u, 114688u);  STAGE(uB, 3u*K64 + 64u,  122880u);
    asm volatile("s_waitcnt vmcnt(4)" ::: "memory");   // tile0 landed
    BARRIER();
    LDA2(aC0, 0u, 0u); LDA2(aC1, 0u, 1u); LDB8(0u);    // frags for W0

    const int NI = K >> 7;
    for (int P = 0; P < NI; ++P) {
        const bool pf = (P + 1 < NI);
        const uint kN1 = ((uint)(2 * P + 1)) << 6;
        const uint kN2 = kN1 + 64u;
        const uint kN3 = kN1 + 128u;

        // ---- W0: acc0,1 (buf0); reload aC* <- buf0 st2,3; stage t+1.A lo
        STAGE(uA, kN1,       65536u);  STAGE(uA, kN1 + K64, 73728u);
        __builtin_amdgcn_s_setprio(1);
        MF8(0, aC0); LDA2(aC0, 0u, 2u);
        MF8(1, aC1); LDA2(aC1, 0u, 3u);
        __builtin_amdgcn_s_setprio(0);
        BARRIER();

        // ---- W1: acc2,3; reload <- buf0 st4,5; stage t+1.A hi
        STAGE(uA, kN1 + 2u*K64, 81920u);  STAGE(uA, kN1 + 3u*K64, 90112u);
        __builtin_amdgcn_s_setprio(1);
        MF8(2, aC0); LDA2(aC0, 0u, 4u);
        MF8(3, aC1); LDA2(aC1, 0u, 5u);
        __builtin_amdgcn_s_setprio(0);
        BARRIER();

        // ---- W2: acc4,5; reload <- buf0 st6,7; stage t+2.B lo; vmcnt
        if (pf) { STAGE(uB, kN2, 32768u); STAGE(uB, kN2 + K64, 40960u); }
        __builtin_amdgcn_s_setprio(1);
        MF8(4, aC0); LDA2(aC0, 0u, 6u);
        MF8(5, aC1); LDA2(aC1, 0u, 7u);
        __builtin_amdgcn_s_setprio(0);
        if (pf) asm volatile("s_waitcnt vmcnt(2)" ::: "memory");
        else    asm volatile("s_waitcnt vmcnt(0)" ::: "memory");
        BARRIER();

        // ---- W3: acc6,7; reload aC* <- buf1 st0,1 + bf <- buf1.B; stage t+2.B hi
        if (pf) { STAGE(uB, kN2 + 2u*K64, 49152u); STAGE(uB, kN2 + 3u*K64, 57344u); }
        __builtin_amdgcn_s_setprio(1);
        MF8(6, aC0); LDA2(aC0, 65536u, 0u);
        MF8(7, aC1); LDA2(aC1, 65536u, 1u);
        __builtin_amdgcn_s_setprio(0);
        LDB8(65536u);
        BARRIER();

        // ---- W4: acc0,1 (buf1); reload <- buf1 st2,3; stage t+2.A lo
        if (pf) { STAGE(uA, kN2, 0u); STAGE(uA, kN2 + K64, 8192u); }
        __builtin_amdgcn_s_setprio(1);
        MF8(0, aC0); LDA2(aC0, 65536u, 2u);
        MF8(1, aC1); LDA2(aC1, 65536u, 3u);
        __builtin_amdgcn_s_setprio(0);
        BARRIER();

        // ---- W5: acc2,3; reload <- buf1 st4,5; stage t+2.A hi
        if (pf) { STAGE(uA, kN2 + 2u*K64, 16384u); STAGE(uA, kN2 + 3u*K64, 24576u); }
        __builtin_amdgcn_s_setprio(1);
        MF8(2, aC0); LDA2(aC0, 65536u, 4u);
        MF8(3, aC1); LDA2(aC1, 65536u, 5u);
        __builtin_amdgcn_s_setprio(0);
        BARRIER();

        // ---- W6: acc4,5; reload <- buf1 st6,7; stage t+3.B lo; vmcnt
        if (pf) { STAGE(uB, kN3, 98304u); STAGE(uB, kN3 + K64, 106496u); }
        __builtin_amdgcn_s_setprio(1);
        MF8(4, aC0); LDA2(aC0, 65536u, 6u);
        MF8(5, aC1); LDA2(aC1, 65536u, 7u);
        __builtin_amdgcn_s_setprio(0);
        if (pf) asm volatile("s_waitcnt vmcnt(2)" ::: "memory");
        BARRIER();

        // ---- W7: acc6,7; reload aC* <- buf0 st0,1 + bf <- buf0.B; stage t+3.B hi
        if (pf) { STAGE(uB, kN3 + 2u*K64, 114688u); STAGE(uB, kN3 + 3u*K64, 122880u); }
        __builtin_amdgcn_s_setprio(1);
        MF8(6, aC0); if (pf) LDA2(aC0, 0u, 0u);
        MF8(7, aC1); if (pf) LDA2(aC1, 0u, 1u);
        __builtin_amdgcn_s_setprio(0);
        if (pf) LDB8(0u);
        BARRIER();
    }

    // ---- epilogue: C/D layout col=lane&15, row=(lane>>4)*4+r ----
    if (EPI == 0) {
        __hip_bfloat16* Cb = (__hip_bfloat16*)Cout;
#pragma unroll
        for (int i = 0; i < 8; ++i)
#pragma unroll
            for (int j = 0; j < 4; ++j)
#pragma unroll
                for (int r = 0; r < 4; ++r) {
                    size_t row = rowBase + wr*128 + i*16 + hi*4 + r;
                    size_t col = colBase + wc*64 + j*16 + lo;
                    float v = fmaxf(acc[i][j][r], 0.0f);
                    Cb[row * N + col] = __float2bfloat16(v * v);
                }
    } else {
        float* Cf = (float*)Cout;
#pragma unroll
        for (int i = 0; i < 8; ++i)
#pragma unroll
            for (int j = 0; j < 4; ++j)
#pragma unroll
                for (int r = 0; r < 4; ++r) {
                    size_t row = rowBase + wr*128 + i*16 + hi*4 + r;
                    size_t col = colBase + wc*64 + j*16 + lo;
                    Cf[row * N + col] = acc[i][j][r];
                }
    }
}

// ---------------------------------------------------------------------------
extern "C" void kernel_launch(void* const* d_in, const int* in_sizes, int n_in,
                              void* d_out, int out_size, void* d_ws, size_t ws_size,
                              hipStream_t stream) {
    const float* x      = (const float*)d_in[0];  // 8192 x 2048
    const float* w_fc   = (const float*)d_in[1];  // 8192 x 2048
    const float* w_proj = (const float*)d_in[2];  // 2048 x 8192
    float* out = (float*)d_out;                   // 8192 x 2048

    const int DIM = 2048, HID = 8192, M = 8192;

    char* ws = (char*)d_ws;
    __hip_bfloat16* Xb  = (__hip_bfloat16*)ws;
    __hip_bfloat16* Wfc = (__hip_bfloat16*)(ws + (size_t)M * DIM * 2);
    __hip_bfloat16* Wpj = (__hip_bfloat16*)(ws + (size_t)(M * DIM + (size_t)HID * DIM) * 2);
    __hip_bfloat16* H2  = (__hip_bfloat16*)(ws + (size_t)(M * DIM + 2 * (size_t)HID * DIM) * 2);

    (void)hipFuncSetAttribute((const void*)gemm256_kernel<0>,
                              hipFuncAttributeMaxDynamicSharedMemorySize, 131072);
    (void)hipFuncSetAttribute((const void*)gemm256_kernel<1>,
                              hipFuncAttributeMaxDynamicSharedMemorySize, 131072);

    int nblk = HID * DIM / 64;
    quant_bf16_kernel<<<nblk / 256, 256, 0, stream>>>(w_fc, Wfc, nblk);
    quant_bf16_kernel<<<nblk / 256, 256, 0, stream>>>(w_proj, Wpj, nblk);

    int n8 = M * DIM / 8;
    f32_to_bf16_kernel<<<n8 / 256, 256, 0, stream>>>(x, Xb, n8);

    // H2 = bf16( relu(X @ Wfc^T)^2 )  [8192 x 8192]
    gemm256_kernel<0><<<(M/256)*(HID/256), 512, 131072, stream>>>(
        Xb, Wfc, (void*)H2, M, HID, DIM);

    // out = H2 @ Wpj^T  [8192 x 2048] f32
    gemm256_kernel<1><<<(M/256)*(DIM/256), 512, 131072, stream>>>(
        H2, Wpj, (void*)out, M, DIM, HID);
}